// Round 1
// baseline (688.004 us; speedup 1.0000x reference)
//
#include <hip/hip_runtime.h>

// ---------------------------------------------------------------------------
// TreeCaps forward, MI355X fp32 implementation.
// Fixed forest: per graph of 1024 nodes, node p's children are 4p+1..4p+4;
// nodes 0..255 are internal (updated each layer), 256..1023 are leaves
// (keep embedding h0 through all layers).
// ---------------------------------------------------------------------------

#define BG      32
#define NPG     1024
#define HH      128
#define NLAY    4
#define INT_PG  256
#define M_INT   8192      // BG*INT_PG
#define NN      32768     // BG*NPG
#define EPG     1023
#define DCC     16
#define NS      50

// ---------------- embedding: h0 = concat(type_emb[t], token_emb[k]) --------
__global__ void k_embed(const int* __restrict__ tids, const int* __restrict__ kids,
                        const float* __restrict__ temb, const float* __restrict__ kemb,
                        float* __restrict__ h) {
  int idx = blockIdx.x * 256 + threadIdx.x;        // NN*32
  int n = idx >> 5, c4 = idx & 31;
  float4 v;
  if (c4 < 16) v = *(const float4*)(temb + tids[n] * 64 + c4 * 4);
  else         v = *(const float4*)(kemb + kids[n] * 64 + (c4 - 16) * 4);
  *(float4*)(h + n * 128 + c4 * 4) = v;
}

// ---------------- per-layer: weighted child sums ---------------------------
__global__ void k_gather(const float* __restrict__ h, const int* __restrict__ src,
                         const float* __restrict__ lw, const float* __restrict__ rw,
                         float* __restrict__ hl, float* __restrict__ hr) {
  int idx = blockIdx.x * 256 + threadIdx.x;        // M_INT*32
  int p = idx >> 5, c4 = idx & 31;
  int g = p >> 8, pl = p & 255;
  float4 al = make_float4(0.f, 0.f, 0.f, 0.f);
  float4 ar = make_float4(0.f, 0.f, 0.f, 0.f);
  for (int j = 0; j < 4; ++j) {
    int cc = 4 * pl + 1 + j;                       // child local id
    if (cc < NPG) {
      int e = g * EPG + cc - 1;
      int child = src[e];                          // global node id
      float lv = lw[e], rv = rw[e];
      float4 hv = *(const float4*)(h + child * 128 + c4 * 4);
      al.x = fmaf(lv, hv.x, al.x); al.y = fmaf(lv, hv.y, al.y);
      al.z = fmaf(lv, hv.z, al.z); al.w = fmaf(lv, hv.w, al.w);
      ar.x = fmaf(rv, hv.x, ar.x); ar.y = fmaf(rv, hv.y, ar.y);
      ar.z = fmaf(rv, hv.z, ar.z); ar.w = fmaf(rv, hv.w, ar.w);
    }
  }
  *(float4*)(hl + p * 128 + c4 * 4) = al;
  *(float4*)(hr + p * 128 + c4 * 4) = ar;
}

// ------------- conv matmul: new_h = relu(hl@Wl + hr@Wr + h@Wt + b) ---------
// [8192 rows, K=384, N=128]; block = 256 thr, 32 rows x 128 cols, 4x4/thread
__global__ __launch_bounds__(256) void k_conv(
    const float* __restrict__ hl, const float* __restrict__ hr,
    float* __restrict__ h,
    const float* __restrict__ Wl, const float* __restrict__ Wr,
    const float* __restrict__ Wt, const float* __restrict__ bias,
    float* __restrict__ feat) {
  __shared__ float Ws[32][128];
  __shared__ float AsT[32][40];   // [k][row], padded
  int tid = threadIdx.x;
  int tx = tid & 31, ty = tid >> 5;
  int rowBase = blockIdx.x * 32;
  int nodeBase = ((rowBase >> 8) << 10) + (rowBase & 255);
  float acc[4][4] = {};
  int sr = tid >> 3, sc4 = (tid & 7) * 4;

  for (int kc = 0; kc < 12; ++kc) {
    int ssel = kc >> 2, kcol = (kc & 3) * 32;
    const float* ap = (ssel == 0) ? (hl + rowBase * 128)
                    : (ssel == 1) ? (hr + rowBase * 128)
                                  : (h + nodeBase * 128);
    const float* wsrc = ((ssel == 0) ? Wl : (ssel == 1) ? Wr : Wt) + kcol * 128;
    float4 av = *(const float4*)(ap + sr * 128 + kcol + sc4);
    float4 wv0, wv1, wv2, wv3;
    {
      int f0 = tid, f1 = tid + 256, f2 = tid + 512, f3 = tid + 768;
      wv0 = *(const float4*)(wsrc + (f0 >> 5) * 128 + (f0 & 31) * 4);
      wv1 = *(const float4*)(wsrc + (f1 >> 5) * 128 + (f1 & 31) * 4);
      wv2 = *(const float4*)(wsrc + (f2 >> 5) * 128 + (f2 & 31) * 4);
      wv3 = *(const float4*)(wsrc + (f3 >> 5) * 128 + (f3 & 31) * 4);
    }
    __syncthreads();
    AsT[sc4 + 0][sr] = av.x; AsT[sc4 + 1][sr] = av.y;
    AsT[sc4 + 2][sr] = av.z; AsT[sc4 + 3][sr] = av.w;
    {
      int f0 = tid, f1 = tid + 256, f2 = tid + 512, f3 = tid + 768;
      *(float4*)&Ws[f0 >> 5][(f0 & 31) * 4] = wv0;
      *(float4*)&Ws[f1 >> 5][(f1 & 31) * 4] = wv1;
      *(float4*)&Ws[f2 >> 5][(f2 & 31) * 4] = wv2;
      *(float4*)&Ws[f3 >> 5][(f3 & 31) * 4] = wv3;
    }
    __syncthreads();
    #pragma unroll
    for (int kk = 0; kk < 32; ++kk) {
      float4 wv = *(float4*)&Ws[kk][tx * 4];
      float4 av2 = *(float4*)&AsT[kk][ty * 4];
      float aa[4] = {av2.x, av2.y, av2.z, av2.w};
      float ww[4] = {wv.x, wv.y, wv.z, wv.w};
      #pragma unroll
      for (int i = 0; i < 4; ++i)
        #pragma unroll
        for (int j = 0; j < 4; ++j)
          acc[i][j] = fmaf(aa[i], ww[j], acc[i][j]);
    }
  }
  float4 bv = *(const float4*)(bias + tx * 4);
  float bb[4] = {bv.x, bv.y, bv.z, bv.w};
  #pragma unroll
  for (int i = 0; i < 4; ++i) {
    int r = ty * 4 + i;
    float4 o = make_float4(fmaxf(acc[i][0] + bb[0], 0.f),
                           fmaxf(acc[i][1] + bb[1], 0.f),
                           fmaxf(acc[i][2] + bb[2], 0.f),
                           fmaxf(acc[i][3] + bb[3], 0.f));
    *(float4*)(feat + (rowBase + r) * 128 + tx * 4) = o;
    *(float4*)(h + (nodeBase + r) * 128 + tx * 4) = o;
  }
}

// ---------------- l2 norms over [H, L] per node ----------------------------
__global__ void k_l2(const float* __restrict__ h, const float* __restrict__ feat,
                     float* __restrict__ l2) {
  int wid = (blockIdx.x * 256 + threadIdx.x) >> 6;   // node id
  int lane = threadIdx.x & 63;
  int g = wid >> 10, local = wid & 1023;
  float s = 0.f;
  if (local >= INT_PG) {                              // leaf: 4*||h0||^2
    const float* p = h + wid * 128;
    float a = p[lane], b = p[lane + 64];
    s = (a * a + b * b) * 4.f;
  } else {
    int row = (g * INT_PG + local) * 128;
    #pragma unroll
    for (int l = 0; l < 4; ++l) {
      const float* p = feat + l * (M_INT * 128) + row;
      float a = p[lane], b = p[lane + 64];
      s += a * a + b * b;
    }
  }
  #pragma unroll
  for (int off = 32; off; off >>= 1) s += __shfl_down(s, off);
  if (lane == 0) l2[wid] = s;
}

// ---------------- top-8 per graph (JAX tie-break: lower index first) -------
__global__ void k_topk(const float* __restrict__ l2, int* __restrict__ sel) {
  __shared__ unsigned long long keys[1024];
  __shared__ unsigned long long red[256];
  int g = blockIdx.x, tid = threadIdx.x;
  for (int i = tid; i < 1024; i += 256) {
    unsigned vb = __float_as_uint(l2[g * 1024 + i]);   // l2 >= 0: uint order ok
    keys[i] = ((unsigned long long)vb << 32) | (unsigned)(~i);
  }
  __syncthreads();
  for (int r = 0; r < 8; ++r) {
    unsigned long long best = 0ULL;
    for (int i = tid; i < 1024; i += 256) {
      unsigned long long k = keys[i];
      best = (k > best) ? k : best;
    }
    red[tid] = best;
    __syncthreads();
    for (int st = 128; st; st >>= 1) {
      if (tid < st) {
        unsigned long long a = red[tid], b = red[tid + st];
        red[tid] = (b > a) ? b : a;
      }
      __syncthreads();
    }
    if (tid == 0) {
      unsigned long long k = red[0];
      int idx = (int)(~(unsigned)(k & 0xffffffffu));
      sel[g * 8 + r] = idx;
      keys[idx] = 0ULL;
    }
    __syncthreads();
  }
}

// ---------------- build U (= initial v_j) [g][1024][4] ---------------------
__global__ void k_buildU(const float* __restrict__ h, const float* __restrict__ feat,
                         const int* __restrict__ sel,
                         float* __restrict__ U, float* __restrict__ Vsum) {
  int idx = blockIdx.x * 256 + threadIdx.x;      // 32768
  int g = idx >> 10, rank = (idx >> 7) & 7, hh = idx & 127;
  int local = sel[g * 8 + rank];
  float4 v;
  if (local >= INT_PG) {
    float x = h[(g * NPG + local) * 128 + hh];
    v = make_float4(x, x, x, x);
  } else {
    int row = (g * INT_PG + local) * 128 + hh;
    v.x = feat[row];
    v.y = feat[M_INT * 128 + row];
    v.z = feat[2 * M_INT * 128 + row];
    v.w = feat[3 * M_INT * 128 + row];
  }
  int o = g * 1024 + rank * 128 + hh;
  ((float4*)U)[o] = v;
  ((float4*)Vsum)[o] = v;
}

// ------------- VTS phase A: per-row softmax stats of alpha = U@Vsum.T ------
__global__ __launch_bounds__(256) void k_vtsA(const float* __restrict__ U,
                                              const float* __restrict__ Vsum,
                                              float* __restrict__ mw, float* __restrict__ sw) {
  __shared__ float4 Vs[1024];
  __shared__ float mrow[128];
  __shared__ float red[256];
  int g = blockIdx.x >> 3, rb = (blockIdx.x & 7) * 128;
  int tid = threadIdx.x, r = tid & 127, half = tid >> 7;
  for (int i = tid; i < 1024; i += 256) Vs[i] = ((const float4*)Vsum)[g * 1024 + i];
  __syncthreads();
  int i = rb + r;
  float4 u = ((const float4*)U)[g * 1024 + i];
  int j0 = half * 512;
  float mmax = -3.4e38f;
  for (int j = j0; j < j0 + 512; ++j) {
    float4 v = Vs[j];
    float a = u.x * v.x + u.y * v.y + u.z * v.z + u.w * v.w;
    mmax = fmaxf(mmax, a);
  }
  red[tid] = mmax;
  __syncthreads();
  if (half == 0) mrow[r] = fmaxf(red[r], red[r + 128]);
  __syncthreads();
  float m = mrow[r];
  float ssum = 0.f;
  for (int j = j0; j < j0 + 512; ++j) {
    float4 v = Vs[j];
    float a = u.x * v.x + u.y * v.y + u.z * v.z + u.w * v.w;
    ssum += __expf(a - m);
  }
  red[tid] = ssum;
  __syncthreads();
  if (half == 0) { mw[g * 1024 + i] = m; sw[g * 1024 + i] = red[r] + red[r + 128]; }
}

// ------------- VTS phase B: Vnew = beta.T @ U; update Vsum or emit SC ------
__global__ __launch_bounds__(256) void k_vtsB(const float* __restrict__ U,
                                              float* __restrict__ Vsum,
                                              const float* __restrict__ mw,
                                              const float* __restrict__ sw,
                                              float* __restrict__ SCT, int last) {
  __shared__ float4 Us[1024];
  __shared__ float mi[1024];
  __shared__ float isi[1024];
  __shared__ float4 par[256];
  int g = blockIdx.x >> 3, cb = (blockIdx.x & 7) * 128;
  int tid = threadIdx.x, c = tid & 127, half = tid >> 7;
  for (int i = tid; i < 1024; i += 256) {
    Us[i] = ((const float4*)U)[g * 1024 + i];
    mi[i] = mw[g * 1024 + i];
    isi[i] = 1.0f / sw[g * 1024 + i];
  }
  __syncthreads();
  int j = cb + c;
  float4 vj = ((const float4*)Vsum)[g * 1024 + j];
  float4 acc = make_float4(0.f, 0.f, 0.f, 0.f);
  int i0 = half * 512;
  for (int i = i0; i < i0 + 512; ++i) {
    float4 uu = Us[i];
    float a = uu.x * vj.x + uu.y * vj.y + uu.z * vj.z + uu.w * vj.w;
    float w = __expf(a - mi[i]) * isi[i];
    acc.x = fmaf(w, uu.x, acc.x); acc.y = fmaf(w, uu.y, acc.y);
    acc.z = fmaf(w, uu.z, acc.z); acc.w = fmaf(w, uu.w, acc.w);
  }
  par[tid] = acc;
  __syncthreads();
  if (half == 0) {
    float4 o = par[tid], p2 = par[tid + 128];
    o.x += p2.x; o.y += p2.y; o.z += p2.z; o.w += p2.w;
    if (last) {
      float sq = o.x * o.x + o.y * o.y + o.z * o.z + o.w * o.w;
      float f = (sq / (1.f + sq)) / (sqrtf(sq + 1e-10f) + 1e-8f);
      // SC_T[j][b][m]
      ((float4*)SCT)[j * 32 + g] = make_float4(o.x * f, o.y * f, o.z * f, o.w * f);
    } else {
      ((float4*)Vsum)[g * 1024 + j] = make_float4(vj.x + o.x, vj.y + o.y,
                                                  vj.z + o.z, vj.w + o.w);
    }
  }
}

// ---------------- Wjm[n][c][s][m] -> W_T[s][n][c][m] -----------------------
__global__ void k_transW(const float* __restrict__ Wjm, float* __restrict__ WT) {
  __shared__ float w[3200];
  int n = blockIdx.x, tid = threadIdx.x;
  for (int i = tid; i < 3200; i += 256) w[i] = Wjm[n * 3200 + i];
  __syncthreads();
  for (int i = tid; i < 3200; i += 256) {
    int s = i >> 6, cm = i & 63, cc = cm >> 2, m = cm & 3;
    WT[(s * 1024 + n) * 64 + cm] = w[(cc * NS + s) * 4 + m];
  }
}

// ---------------- gamma = softmax_s(delta), layouts [s][n][b] --------------
__global__ void k_gamma(const float* __restrict__ delta, float* __restrict__ gT) {
  int idx = blockIdx.x * 256 + threadIdx.x;    // 32768 = (n,b)
  int b = idx & 31, n = idx >> 5;
  const float* dp = delta + n * 32 + b;        // s-stride = 32768 floats
  float m = -3.4e38f;
  for (int s = 0; s < NS; ++s) m = fmaxf(m, dp[s * 32768]);
  float sum = 0.f;
  for (int s = 0; s < NS; ++s) sum += __expf(dp[s * 32768] - m);
  float inv = 1.0f / sum;
  float* gp = gT + n * 32 + b;
  for (int s = 0; s < NS; ++s) gp[s * 32768] = __expf(dp[s * 32768] - m) * inv;
}

// ------------- Z sweep: accZ[b][s][c] += sum_n gamma * v -------------------
__global__ __launch_bounds__(256) void k_zsweep(const float* __restrict__ WT,
                                                const float* __restrict__ SCT,
                                                const float* __restrict__ gT,
                                                float* __restrict__ accZ, int it0) {
  int sb = blockIdx.x >> 3, nb = blockIdx.x & 7;
  int tid = threadIdx.x;
  int b = tid & 31, ch = tid >> 5;             // ch in 0..7: c = ch, ch+8
  int n0 = nb * 128;
  const float4* wt = (const float4*)WT + (sb * 1024 + n0) * 16;
  const float4* sct = (const float4*)SCT + n0 * 32 + b;
  const float* gp = gT + (sb * 1024 + n0) * 32 + b;
  float a0 = 0.f, a1 = 0.f;
  for (int nn = 0; nn < 128; ++nn) {
    float4 w0 = wt[nn * 16 + ch];
    float4 w1 = wt[nn * 16 + ch + 8];
    float4 s4 = sct[nn * 32];
    float gm = it0 ? (1.0f / 50.0f) : gp[nn * 32];
    float t0 = w0.x * s4.x + w0.y * s4.y + w0.z * s4.z + w0.w * s4.w;
    float t1 = w1.x * s4.x + w1.y * s4.y + w1.z * s4.z + w1.w * s4.w;
    a0 = fmaf(gm, t0, a0);
    a1 = fmaf(gm, t1, a1);
  }
  atomicAdd(accZ + (b * NS + sb) * 16 + ch, a0);
  atomicAdd(accZ + (b * NS + sb) * 16 + ch + 8, a1);
}

// ---------------- squash accZ -> z; final: logits --------------------------
__global__ void k_squash(const float* __restrict__ accZ, float* __restrict__ z,
                         float* __restrict__ out, int fin) {
  int idx = blockIdx.x * 256 + threadIdx.x;
  if (idx >= 1600) return;
  const float4* a4 = (const float4*)accZ + idx * 4;
  float4 u0 = a4[0], u1 = a4[1], u2 = a4[2], u3 = a4[3];
  float sq = u0.x * u0.x + u0.y * u0.y + u0.z * u0.z + u0.w * u0.w
           + u1.x * u1.x + u1.y * u1.y + u1.z * u1.z + u1.w * u1.w
           + u2.x * u2.x + u2.y * u2.y + u2.z * u2.z + u2.w * u2.w
           + u3.x * u3.x + u3.y * u3.y + u3.z * u3.z + u3.w * u3.w;
  float f = (sq / (1.f + sq)) / (sqrtf(sq + 1e-10f) + 1e-8f);
  if (fin) {
    float lg = sqrtf(sq * f * f + 1e-10f);
    out[idx] = lg;
    out[idx + 1600] = lg;
  } else {
    float4* z4 = (float4*)z + idx * 4;
    z4[0] = make_float4(u0.x * f, u0.y * f, u0.z * f, u0.w * f);
    z4[1] = make_float4(u1.x * f, u1.y * f, u1.z * f, u1.w * f);
    z4[2] = make_float4(u2.x * f, u2.y * f, u2.z * f, u2.w * f);
    z4[3] = make_float4(u3.x * f, u3.y * f, u3.z * f, u3.w * f);
  }
}

// ------------- D sweep: delta[s][n][b] (+)= sum_c v[b,n,s,c]*z[b,s,c] ------
__global__ __launch_bounds__(256) void k_dsweep(const float* __restrict__ WT,
                                                const float* __restrict__ SCT,
                                                const float* __restrict__ z,
                                                float* __restrict__ delta, int first) {
  __shared__ float wl[50 * 68];     // [s][c][m], row stride 68
  __shared__ float zl[8 * 50 * 20]; // [b8*50+s][c], row stride 20
  int n = blockIdx.x >> 2, bq = blockIdx.x & 3;
  int b0 = bq * 8;
  int tid = threadIdx.x;
  for (int i = tid; i < 3200; i += 256) {
    int s = i >> 6, cm = i & 63;
    wl[s * 68 + cm] = WT[(s * 1024 + n) * 64 + cm];
  }
  for (int i = tid; i < 6400; i += 256) {
    int row = i >> 4, c = i & 15;
    zl[row * 20 + c] = z[b0 * 800 + i];   // z[b][s][c] contiguous slice for 8 b's
  }
  __syncthreads();
  for (int idx = tid; idx < 400; idx += 256) {
    int s = idx >> 3, b8 = idx & 7;
    const float4* wp = (const float4*)(wl + s * 68);
    const float4* zp = (const float4*)(zl + (b8 * 50 + s) * 20);
    float4 z0 = zp[0], z1 = zp[1], z2 = zp[2], z3 = zp[3];
    float zs[16] = {z0.x, z0.y, z0.z, z0.w, z1.x, z1.y, z1.z, z1.w,
                    z2.x, z2.y, z2.z, z2.w, z3.x, z3.y, z3.z, z3.w};
    float4 y = make_float4(0.f, 0.f, 0.f, 0.f);
    #pragma unroll
    for (int c = 0; c < 16; ++c) {
      float4 w = wp[c];
      float zc = zs[c];
      y.x = fmaf(zc, w.x, y.x); y.y = fmaf(zc, w.y, y.y);
      y.z = fmaf(zc, w.z, y.z); y.w = fmaf(zc, w.w, y.w);
    }
    float4 sc = ((const float4*)SCT)[n * 32 + b0 + b8];
    float dd = sc.x * y.x + sc.y * y.y + sc.z * y.z + sc.w * y.w;
    float* dp = delta + (s * 1024 + n) * 32 + b0 + b8;
    if (first) *dp = dd; else *dp = *dp + dd;
  }
}

// ---------------------------------------------------------------------------
extern "C" void kernel_launch(void* const* d_in, const int* in_sizes, int n_in,
                              void* d_out, int out_size, void* d_ws, size_t ws_size,
                              hipStream_t stream) {
  const int*   type_ids  = (const int*)d_in[0];
  const int*   token_ids = (const int*)d_in[1];
  const int*   src       = (const int*)d_in[2];
  const float* lw        = (const float*)d_in[4];
  const float* rw        = (const float*)d_in[5];
  const float* temb      = (const float*)d_in[7];
  const float* kemb      = (const float*)d_in[8];
  const float* Wl        = (const float*)d_in[9];
  const float* Wr        = (const float*)d_in[10];
  const float* Wt        = (const float*)d_in[11];
  const float* bconv     = (const float*)d_in[12];
  const float* Wjm       = (const float*)d_in[13];
  float* out = (float*)d_out;
  char* wsb = (char*)d_ws;

  // workspace layout (regions reused across phases; peak 42 MB)
  float* h     = (float*)(wsb + 0);          // 16.78 MB   (dead after buildU)
  float* WT    = (float*)(wsb + 0);          // 12.5  MB   (overlays h)
  float* feat  = (float*)(wsb + 16777216);   // 16.78 MB   (dead after buildU)
  float* gT    = (float*)(wsb + 16777216);   // 6.55  MB   (overlays feat)
  float* delta = (float*)(wsb + 23330816);   // 6.55  MB
  float* accZ  = (float*)(wsb + 29884416);   // 102 KB
  float* zbuf  = (float*)(wsb + 29986816);   // 102 KB
  float* hl    = (float*)(wsb + 33554432);   // 4.19 MB    (dead after conv)
  float* hr    = (float*)(wsb + 37748736);   // 4.19 MB
  float* l2b   = (float*)(wsb + 33554432);   // 128 KB     (overlays hl)
  int*   sel   = (int*)  (wsb + 33685504);   // 1 KB
  float* U     = (float*)(wsb + 33686528);   // 512 KB
  float* Vsum  = (float*)(wsb + 34210816);   // 512 KB
  float* mw    = (float*)(wsb + 34735104);   // 128 KB
  float* sw    = (float*)(wsb + 34866176);   // 128 KB
  float* SCT   = (float*)(wsb + 34997248);   // 512 KB

  k_embed<<<4096, 256, 0, stream>>>(type_ids, token_ids, temb, kemb, h);

  for (int l = 0; l < NLAY; ++l) {
    k_gather<<<1024, 256, 0, stream>>>(h, src, lw, rw, hl, hr);
    k_conv<<<256, 256, 0, stream>>>(hl, hr, h,
                                    Wl + l * 16384, Wr + l * 16384, Wt + l * 16384,
                                    bconv + l * 128, feat + l * (M_INT * 128));
  }

  k_l2<<<8192, 256, 0, stream>>>(h, feat, l2b);
  k_topk<<<32, 256, 0, stream>>>(l2b, sel);
  k_buildU<<<128, 256, 0, stream>>>(h, feat, sel, U, Vsum);
  k_transW<<<1024, 256, 0, stream>>>(Wjm, WT);   // after buildU: h is dead

  for (int it = 0; it < 3; ++it) {
    k_vtsA<<<256, 256, 0, stream>>>(U, Vsum, mw, sw);
    k_vtsB<<<256, 256, 0, stream>>>(U, Vsum, mw, sw, SCT, it == 2 ? 1 : 0);
  }

  for (int it = 0; it < 3; ++it) {
    if (it > 0) k_gamma<<<128, 256, 0, stream>>>(delta, gT);
    hipMemsetAsync(accZ, 0, 32 * 50 * 16 * 4, stream);
    k_zsweep<<<400, 256, 0, stream>>>(WT, SCT, gT, accZ, it == 0 ? 1 : 0);
    k_squash<<<7, 256, 0, stream>>>(accZ, zbuf, out, it == 2 ? 1 : 0);
    if (it < 2) k_dsweep<<<4096, 256, 0, stream>>>(WT, SCT, zbuf, delta, it == 0 ? 1 : 0);
  }
}

// Round 2
// 560.636 us; speedup vs baseline: 1.2272x; 1.2272x over previous
//
#include <hip/hip_runtime.h>

// ---------------------------------------------------------------------------
// TreeCaps forward, MI355X fp32 implementation.
// Fixed forest: per graph of 1024 nodes, node p's children are 4p+1..4p+4;
// nodes 0..255 are internal (updated each layer), 256..1023 are leaves
// (keep embedding h0 through all layers).
// R1: VTS routing kernels widened to 1024-thread blocks (16 waves/CU vs 4),
//     2 rows/cols per thread so each broadcast LDS read feeds 2 dots.
// ---------------------------------------------------------------------------

#define BG      32
#define NPG     1024
#define HH      128
#define NLAY    4
#define INT_PG  256
#define M_INT   8192      // BG*INT_PG
#define NN      32768     // BG*NPG
#define EPG     1023
#define DCC     16
#define NS      50

// ---------------- embedding: h0 = concat(type_emb[t], token_emb[k]) --------
__global__ void k_embed(const int* __restrict__ tids, const int* __restrict__ kids,
                        const float* __restrict__ temb, const float* __restrict__ kemb,
                        float* __restrict__ h) {
  int idx = blockIdx.x * 256 + threadIdx.x;        // NN*32
  int n = idx >> 5, c4 = idx & 31;
  float4 v;
  if (c4 < 16) v = *(const float4*)(temb + tids[n] * 64 + c4 * 4);
  else         v = *(const float4*)(kemb + kids[n] * 64 + (c4 - 16) * 4);
  *(float4*)(h + n * 128 + c4 * 4) = v;
}

// ---------------- per-layer: weighted child sums ---------------------------
__global__ void k_gather(const float* __restrict__ h, const int* __restrict__ src,
                         const float* __restrict__ lw, const float* __restrict__ rw,
                         float* __restrict__ hl, float* __restrict__ hr) {
  int idx = blockIdx.x * 256 + threadIdx.x;        // M_INT*32
  int p = idx >> 5, c4 = idx & 31;
  int g = p >> 8, pl = p & 255;
  float4 al = make_float4(0.f, 0.f, 0.f, 0.f);
  float4 ar = make_float4(0.f, 0.f, 0.f, 0.f);
  for (int j = 0; j < 4; ++j) {
    int cc = 4 * pl + 1 + j;                       // child local id
    if (cc < NPG) {
      int e = g * EPG + cc - 1;
      int child = src[e];                          // global node id
      float lv = lw[e], rv = rw[e];
      float4 hv = *(const float4*)(h + child * 128 + c4 * 4);
      al.x = fmaf(lv, hv.x, al.x); al.y = fmaf(lv, hv.y, al.y);
      al.z = fmaf(lv, hv.z, al.z); al.w = fmaf(lv, hv.w, al.w);
      ar.x = fmaf(rv, hv.x, ar.x); ar.y = fmaf(rv, hv.y, ar.y);
      ar.z = fmaf(rv, hv.z, ar.z); ar.w = fmaf(rv, hv.w, ar.w);
    }
  }
  *(float4*)(hl + p * 128 + c4 * 4) = al;
  *(float4*)(hr + p * 128 + c4 * 4) = ar;
}

// ------------- conv matmul: new_h = relu(hl@Wl + hr@Wr + h@Wt + b) ---------
// [8192 rows, K=384, N=128]; block = 256 thr, 32 rows x 128 cols, 4x4/thread
__global__ __launch_bounds__(256) void k_conv(
    const float* __restrict__ hl, const float* __restrict__ hr,
    float* __restrict__ h,
    const float* __restrict__ Wl, const float* __restrict__ Wr,
    const float* __restrict__ Wt, const float* __restrict__ bias,
    float* __restrict__ feat) {
  __shared__ float Ws[32][128];
  __shared__ float AsT[32][40];   // [k][row], padded
  int tid = threadIdx.x;
  int tx = tid & 31, ty = tid >> 5;
  int rowBase = blockIdx.x * 32;
  int nodeBase = ((rowBase >> 8) << 10) + (rowBase & 255);
  float acc[4][4] = {};
  int sr = tid >> 3, sc4 = (tid & 7) * 4;

  for (int kc = 0; kc < 12; ++kc) {
    int ssel = kc >> 2, kcol = (kc & 3) * 32;
    const float* ap = (ssel == 0) ? (hl + rowBase * 128)
                    : (ssel == 1) ? (hr + rowBase * 128)
                                  : (h + nodeBase * 128);
    const float* wsrc = ((ssel == 0) ? Wl : (ssel == 1) ? Wr : Wt) + kcol * 128;
    float4 av = *(const float4*)(ap + sr * 128 + kcol + sc4);
    float4 wv0, wv1, wv2, wv3;
    {
      int f0 = tid, f1 = tid + 256, f2 = tid + 512, f3 = tid + 768;
      wv0 = *(const float4*)(wsrc + (f0 >> 5) * 128 + (f0 & 31) * 4);
      wv1 = *(const float4*)(wsrc + (f1 >> 5) * 128 + (f1 & 31) * 4);
      wv2 = *(const float4*)(wsrc + (f2 >> 5) * 128 + (f2 & 31) * 4);
      wv3 = *(const float4*)(wsrc + (f3 >> 5) * 128 + (f3 & 31) * 4);
    }
    __syncthreads();
    AsT[sc4 + 0][sr] = av.x; AsT[sc4 + 1][sr] = av.y;
    AsT[sc4 + 2][sr] = av.z; AsT[sc4 + 3][sr] = av.w;
    {
      int f0 = tid, f1 = tid + 256, f2 = tid + 512, f3 = tid + 768;
      *(float4*)&Ws[f0 >> 5][(f0 & 31) * 4] = wv0;
      *(float4*)&Ws[f1 >> 5][(f1 & 31) * 4] = wv1;
      *(float4*)&Ws[f2 >> 5][(f2 & 31) * 4] = wv2;
      *(float4*)&Ws[f3 >> 5][(f3 & 31) * 4] = wv3;
    }
    __syncthreads();
    #pragma unroll
    for (int kk = 0; kk < 32; ++kk) {
      float4 wv = *(float4*)&Ws[kk][tx * 4];
      float4 av2 = *(float4*)&AsT[kk][ty * 4];
      float aa[4] = {av2.x, av2.y, av2.z, av2.w};
      float ww[4] = {wv.x, wv.y, wv.z, wv.w};
      #pragma unroll
      for (int i = 0; i < 4; ++i)
        #pragma unroll
        for (int j = 0; j < 4; ++j)
          acc[i][j] = fmaf(aa[i], ww[j], acc[i][j]);
    }
  }
  float4 bv = *(const float4*)(bias + tx * 4);
  float bb[4] = {bv.x, bv.y, bv.z, bv.w};
  #pragma unroll
  for (int i = 0; i < 4; ++i) {
    int r = ty * 4 + i;
    float4 o = make_float4(fmaxf(acc[i][0] + bb[0], 0.f),
                           fmaxf(acc[i][1] + bb[1], 0.f),
                           fmaxf(acc[i][2] + bb[2], 0.f),
                           fmaxf(acc[i][3] + bb[3], 0.f));
    *(float4*)(feat + (rowBase + r) * 128 + tx * 4) = o;
    *(float4*)(h + (nodeBase + r) * 128 + tx * 4) = o;
  }
}

// ---------------- l2 norms over [H, L] per node ----------------------------
__global__ void k_l2(const float* __restrict__ h, const float* __restrict__ feat,
                     float* __restrict__ l2) {
  int wid = (blockIdx.x * 256 + threadIdx.x) >> 6;   // node id
  int lane = threadIdx.x & 63;
  int g = wid >> 10, local = wid & 1023;
  float s = 0.f;
  if (local >= INT_PG) {                              // leaf: 4*||h0||^2
    const float* p = h + wid * 128;
    float a = p[lane], b = p[lane + 64];
    s = (a * a + b * b) * 4.f;
  } else {
    int row = (g * INT_PG + local) * 128;
    #pragma unroll
    for (int l = 0; l < 4; ++l) {
      const float* p = feat + l * (M_INT * 128) + row;
      float a = p[lane], b = p[lane + 64];
      s += a * a + b * b;
    }
  }
  #pragma unroll
  for (int off = 32; off; off >>= 1) s += __shfl_down(s, off);
  if (lane == 0) l2[wid] = s;
}

// ---------------- top-8 per graph (JAX tie-break: lower index first) -------
__global__ void k_topk(const float* __restrict__ l2, int* __restrict__ sel) {
  __shared__ unsigned long long keys[1024];
  __shared__ unsigned long long red[256];
  int g = blockIdx.x, tid = threadIdx.x;
  for (int i = tid; i < 1024; i += 256) {
    unsigned vb = __float_as_uint(l2[g * 1024 + i]);   // l2 >= 0: uint order ok
    keys[i] = ((unsigned long long)vb << 32) | (unsigned)(~i);
  }
  __syncthreads();
  for (int r = 0; r < 8; ++r) {
    unsigned long long best = 0ULL;
    for (int i = tid; i < 1024; i += 256) {
      unsigned long long k = keys[i];
      best = (k > best) ? k : best;
    }
    red[tid] = best;
    __syncthreads();
    for (int st = 128; st; st >>= 1) {
      if (tid < st) {
        unsigned long long a = red[tid], b = red[tid + st];
        red[tid] = (b > a) ? b : a;
      }
      __syncthreads();
    }
    if (tid == 0) {
      unsigned long long k = red[0];
      int idx = (int)(~(unsigned)(k & 0xffffffffu));
      sel[g * 8 + r] = idx;
      keys[idx] = 0ULL;
    }
    __syncthreads();
  }
}

// ---------------- build U (= initial v_j) [g][1024][4] ---------------------
__global__ void k_buildU(const float* __restrict__ h, const float* __restrict__ feat,
                         const int* __restrict__ sel,
                         float* __restrict__ U, float* __restrict__ Vsum) {
  int idx = blockIdx.x * 256 + threadIdx.x;      // 32768
  int g = idx >> 10, rank = (idx >> 7) & 7, hh = idx & 127;
  int local = sel[g * 8 + rank];
  float4 v;
  if (local >= INT_PG) {
    float x = h[(g * NPG + local) * 128 + hh];
    v = make_float4(x, x, x, x);
  } else {
    int row = (g * INT_PG + local) * 128 + hh;
    v.x = feat[row];
    v.y = feat[M_INT * 128 + row];
    v.z = feat[2 * M_INT * 128 + row];
    v.w = feat[3 * M_INT * 128 + row];
  }
  int o = g * 1024 + rank * 128 + hh;
  ((float4*)U)[o] = v;
  ((float4*)Vsum)[o] = v;
}

// ------------- VTS phase A: per-row softmax stats of alpha = U@Vsum.T ------
// 1024 thr: l = tid&63 -> rows rb+l, rb+64+l; p = tid>>6 -> j in [64p,64p+64)
__global__ __launch_bounds__(1024) void k_vtsA(const float* __restrict__ U,
                                               const float* __restrict__ Vsum,
                                               float* __restrict__ mw, float* __restrict__ sw) {
  __shared__ float4 Vs[1024];     // 16 KB
  __shared__ float2 red[1024];    // 8 KB
  int g = blockIdx.x >> 3, rb = (blockIdx.x & 7) * 128;
  int tid = threadIdx.x, l = tid & 63, p = tid >> 6;
  Vs[tid] = ((const float4*)Vsum)[g * 1024 + tid];
  __syncthreads();
  float4 u0 = ((const float4*)U)[g * 1024 + rb + l];
  float4 u1 = ((const float4*)U)[g * 1024 + rb + 64 + l];
  int j0 = p * 64;
  float m0 = -3.4e38f, m1 = -3.4e38f;
  for (int j = j0; j < j0 + 64; ++j) {
    float4 v = Vs[j];                                  // broadcast across wave
    float a0 = u0.x * v.x + u0.y * v.y + u0.z * v.z + u0.w * v.w;
    float a1 = u1.x * v.x + u1.y * v.y + u1.z * v.z + u1.w * v.w;
    m0 = fmaxf(m0, a0); m1 = fmaxf(m1, a1);
  }
  red[tid] = make_float2(m0, m1);
  __syncthreads();
  #pragma unroll
  for (int st = 512; st >= 64; st >>= 1) {
    if (tid < st) {
      float2 a = red[tid], b = red[tid + st];
      red[tid] = make_float2(fmaxf(a.x, b.x), fmaxf(a.y, b.y));
    }
    __syncthreads();
  }
  float2 mm = red[l];
  __syncthreads();                                     // all reads of red done
  float s0 = 0.f, s1 = 0.f;
  for (int j = j0; j < j0 + 64; ++j) {
    float4 v = Vs[j];
    float a0 = u0.x * v.x + u0.y * v.y + u0.z * v.z + u0.w * v.w;
    float a1 = u1.x * v.x + u1.y * v.y + u1.z * v.z + u1.w * v.w;
    s0 += __expf(a0 - mm.x);
    s1 += __expf(a1 - mm.y);
  }
  red[tid] = make_float2(s0, s1);
  __syncthreads();
  #pragma unroll
  for (int st = 512; st >= 64; st >>= 1) {
    if (tid < st) {
      float2 a = red[tid], b = red[tid + st];
      red[tid] = make_float2(a.x + b.x, a.y + b.y);
    }
    __syncthreads();
  }
  if (tid < 64) {
    float2 ss = red[tid];
    mw[g * 1024 + rb + tid] = mm.x;
    mw[g * 1024 + rb + 64 + tid] = mm.y;
    sw[g * 1024 + rb + tid] = ss.x;
    sw[g * 1024 + rb + 64 + tid] = ss.y;
  }
}

// ------------- VTS phase B: Vnew = beta.T @ U; update Vsum or emit SC ------
// 1024 thr: l = tid&63 -> cols cb+l, cb+64+l; p = tid>>6 -> i in [64p,64p+64)
__global__ __launch_bounds__(1024) void k_vtsB(const float* __restrict__ U,
                                               float* __restrict__ Vsum,
                                               const float* __restrict__ mw,
                                               const float* __restrict__ sw,
                                               float* __restrict__ SCT, int last) {
  __shared__ float4 Us[1024];     // 16 KB
  __shared__ float2 ms[1024];     // 8 KB (m, 1/s)
  __shared__ float4 par[1024];    // 16 KB
  int g = blockIdx.x >> 3, cb = (blockIdx.x & 7) * 128;
  int tid = threadIdx.x, l = tid & 63, p = tid >> 6;
  Us[tid] = ((const float4*)U)[g * 1024 + tid];
  ms[tid] = make_float2(mw[g * 1024 + tid], 1.0f / sw[g * 1024 + tid]);
  __syncthreads();
  float4 v0 = ((const float4*)Vsum)[g * 1024 + cb + l];
  float4 v1 = ((const float4*)Vsum)[g * 1024 + cb + 64 + l];
  float4 acc0 = make_float4(0.f, 0.f, 0.f, 0.f);
  float4 acc1 = make_float4(0.f, 0.f, 0.f, 0.f);
  int i0 = p * 64;
  for (int i = i0; i < i0 + 64; ++i) {
    float4 uu = Us[i];                                 // broadcast across wave
    float2 st = ms[i];
    float a0 = uu.x * v0.x + uu.y * v0.y + uu.z * v0.z + uu.w * v0.w;
    float a1 = uu.x * v1.x + uu.y * v1.y + uu.z * v1.z + uu.w * v1.w;
    float w0 = __expf(a0 - st.x) * st.y;
    float w1 = __expf(a1 - st.x) * st.y;
    acc0.x = fmaf(w0, uu.x, acc0.x); acc0.y = fmaf(w0, uu.y, acc0.y);
    acc0.z = fmaf(w0, uu.z, acc0.z); acc0.w = fmaf(w0, uu.w, acc0.w);
    acc1.x = fmaf(w1, uu.x, acc1.x); acc1.y = fmaf(w1, uu.y, acc1.y);
    acc1.z = fmaf(w1, uu.z, acc1.z); acc1.w = fmaf(w1, uu.w, acc1.w);
  }
  par[tid] = acc0;
  __syncthreads();
  #pragma unroll
  for (int st = 512; st >= 64; st >>= 1) {
    if (tid < st) {
      float4 a = par[tid], b = par[tid + st];
      par[tid] = make_float4(a.x + b.x, a.y + b.y, a.z + b.z, a.w + b.w);
    }
    __syncthreads();
  }
  float4 o0;
  if (tid < 64) o0 = par[tid];
  __syncthreads();
  par[tid] = acc1;
  __syncthreads();
  #pragma unroll
  for (int st = 512; st >= 64; st >>= 1) {
    if (tid < st) {
      float4 a = par[tid], b = par[tid + st];
      par[tid] = make_float4(a.x + b.x, a.y + b.y, a.z + b.z, a.w + b.w);
    }
    __syncthreads();
  }
  if (tid < 64) {
    float4 o1 = par[tid];
    int j0c = cb + tid, j1c = cb + 64 + tid;
    if (last) {
      float sq0 = o0.x * o0.x + o0.y * o0.y + o0.z * o0.z + o0.w * o0.w;
      float f0 = (sq0 / (1.f + sq0)) / (sqrtf(sq0 + 1e-10f) + 1e-8f);
      ((float4*)SCT)[j0c * 32 + g] = make_float4(o0.x * f0, o0.y * f0, o0.z * f0, o0.w * f0);
      float sq1 = o1.x * o1.x + o1.y * o1.y + o1.z * o1.z + o1.w * o1.w;
      float f1 = (sq1 / (1.f + sq1)) / (sqrtf(sq1 + 1e-10f) + 1e-8f);
      ((float4*)SCT)[j1c * 32 + g] = make_float4(o1.x * f1, o1.y * f1, o1.z * f1, o1.w * f1);
    } else {
      float4 w0 = ((const float4*)Vsum)[g * 1024 + j0c];
      float4 w1 = ((const float4*)Vsum)[g * 1024 + j1c];
      ((float4*)Vsum)[g * 1024 + j0c] = make_float4(w0.x + o0.x, w0.y + o0.y,
                                                    w0.z + o0.z, w0.w + o0.w);
      ((float4*)Vsum)[g * 1024 + j1c] = make_float4(w1.x + o1.x, w1.y + o1.y,
                                                    w1.z + o1.z, w1.w + o1.w);
    }
  }
}

// ---------------- Wjm[n][c][s][m] -> W_T[s][n][c][m] -----------------------
__global__ void k_transW(const float* __restrict__ Wjm, float* __restrict__ WT) {
  __shared__ float w[3200];
  int n = blockIdx.x, tid = threadIdx.x;
  for (int i = tid; i < 3200; i += 256) w[i] = Wjm[n * 3200 + i];
  __syncthreads();
  for (int i = tid; i < 3200; i += 256) {
    int s = i >> 6, cm = i & 63, cc = cm >> 2, m = cm & 3;
    WT[(s * 1024 + n) * 64 + cm] = w[(cc * NS + s) * 4 + m];
  }
}

// ---------------- gamma = softmax_s(delta), layouts [s][n][b] --------------
__global__ void k_gamma(const float* __restrict__ delta, float* __restrict__ gT) {
  int idx = blockIdx.x * 256 + threadIdx.x;    // 32768 = (n,b)
  int b = idx & 31, n = idx >> 5;
  const float* dp = delta + n * 32 + b;        // s-stride = 32768 floats
  float m = -3.4e38f;
  for (int s = 0; s < NS; ++s) m = fmaxf(m, dp[s * 32768]);
  float sum = 0.f;
  for (int s = 0; s < NS; ++s) sum += __expf(dp[s * 32768] - m);
  float inv = 1.0f / sum;
  float* gp = gT + n * 32 + b;
  for (int s = 0; s < NS; ++s) gp[s * 32768] = __expf(dp[s * 32768] - m) * inv;
}

// ------------- Z sweep: accZ[b][s][c] += sum_n gamma * v -------------------
__global__ __launch_bounds__(256) void k_zsweep(const float* __restrict__ WT,
                                                const float* __restrict__ SCT,
                                                const float* __restrict__ gT,
                                                float* __restrict__ accZ, int it0) {
  int sb = blockIdx.x >> 3, nb = blockIdx.x & 7;
  int tid = threadIdx.x;
  int b = tid & 31, ch = tid >> 5;             // ch in 0..7: c = ch, ch+8
  int n0 = nb * 128;
  const float4* wt = (const float4*)WT + (sb * 1024 + n0) * 16;
  const float4* sct = (const float4*)SCT + n0 * 32 + b;
  const float* gp = gT + (sb * 1024 + n0) * 32 + b;
  float a0 = 0.f, a1 = 0.f;
  for (int nn = 0; nn < 128; ++nn) {
    float4 w0 = wt[nn * 16 + ch];
    float4 w1 = wt[nn * 16 + ch + 8];
    float4 s4 = sct[nn * 32];
    float gm = it0 ? (1.0f / 50.0f) : gp[nn * 32];
    float t0 = w0.x * s4.x + w0.y * s4.y + w0.z * s4.z + w0.w * s4.w;
    float t1 = w1.x * s4.x + w1.y * s4.y + w1.z * s4.z + w1.w * s4.w;
    a0 = fmaf(gm, t0, a0);
    a1 = fmaf(gm, t1, a1);
  }
  atomicAdd(accZ + (b * NS + sb) * 16 + ch, a0);
  atomicAdd(accZ + (b * NS + sb) * 16 + ch + 8, a1);
}

// ---------------- squash accZ -> z; final: logits --------------------------
__global__ void k_squash(const float* __restrict__ accZ, float* __restrict__ z,
                         float* __restrict__ out, int fin) {
  int idx = blockIdx.x * 256 + threadIdx.x;
  if (idx >= 1600) return;
  const float4* a4 = (const float4*)accZ + idx * 4;
  float4 u0 = a4[0], u1 = a4[1], u2 = a4[2], u3 = a4[3];
  float sq = u0.x * u0.x + u0.y * u0.y + u0.z * u0.z + u0.w * u0.w
           + u1.x * u1.x + u1.y * u1.y + u1.z * u1.z + u1.w * u1.w
           + u2.x * u2.x + u2.y * u2.y + u2.z * u2.z + u2.w * u2.w
           + u3.x * u3.x + u3.y * u3.y + u3.z * u3.z + u3.w * u3.w;
  float f = (sq / (1.f + sq)) / (sqrtf(sq + 1e-10f) + 1e-8f);
  if (fin) {
    float lg = sqrtf(sq * f * f + 1e-10f);
    out[idx] = lg;
    out[idx + 1600] = lg;
  } else {
    float4* z4 = (float4*)z + idx * 4;
    z4[0] = make_float4(u0.x * f, u0.y * f, u0.z * f, u0.w * f);
    z4[1] = make_float4(u1.x * f, u1.y * f, u1.z * f, u1.w * f);
    z4[2] = make_float4(u2.x * f, u2.y * f, u2.z * f, u2.w * f);
    z4[3] = make_float4(u3.x * f, u3.y * f, u3.z * f, u3.w * f);
  }
}

// ------------- D sweep: delta[s][n][b] (+)= sum_c v[b,n,s,c]*z[b,s,c] ------
__global__ __launch_bounds__(256) void k_dsweep(const float* __restrict__ WT,
                                                const float* __restrict__ SCT,
                                                const float* __restrict__ z,
                                                float* __restrict__ delta, int first) {
  __shared__ float wl[50 * 68];     // [s][c][m], row stride 68
  __shared__ float zl[8 * 50 * 20]; // [b8*50+s][c], row stride 20
  int n = blockIdx.x >> 2, bq = blockIdx.x & 3;
  int b0 = bq * 8;
  int tid = threadIdx.x;
  for (int i = tid; i < 3200; i += 256) {
    int s = i >> 6, cm = i & 63;
    wl[s * 68 + cm] = WT[(s * 1024 + n) * 64 + cm];
  }
  for (int i = tid; i < 6400; i += 256) {
    int row = i >> 4, c = i & 15;
    zl[row * 20 + c] = z[b0 * 800 + i];   // z[b][s][c] contiguous slice for 8 b's
  }
  __syncthreads();
  for (int idx = tid; idx < 400; idx += 256) {
    int s = idx >> 3, b8 = idx & 7;
    const float4* wp = (const float4*)(wl + s * 68);
    const float4* zp = (const float4*)(zl + (b8 * 50 + s) * 20);
    float4 z0 = zp[0], z1 = zp[1], z2 = zp[2], z3 = zp[3];
    float zs[16] = {z0.x, z0.y, z0.z, z0.w, z1.x, z1.y, z1.z, z1.w,
                    z2.x, z2.y, z2.z, z2.w, z3.x, z3.y, z3.z, z3.w};
    float4 y = make_float4(0.f, 0.f, 0.f, 0.f);
    #pragma unroll
    for (int c = 0; c < 16; ++c) {
      float4 w = wp[c];
      float zc = zs[c];
      y.x = fmaf(zc, w.x, y.x); y.y = fmaf(zc, w.y, y.y);
      y.z = fmaf(zc, w.z, y.z); y.w = fmaf(zc, w.w, y.w);
    }
    float4 sc = ((const float4*)SCT)[n * 32 + b0 + b8];
    float dd = sc.x * y.x + sc.y * y.y + sc.z * y.z + sc.w * y.w;
    float* dp = delta + (s * 1024 + n) * 32 + b0 + b8;
    if (first) *dp = dd; else *dp = *dp + dd;
  }
}

// ---------------------------------------------------------------------------
extern "C" void kernel_launch(void* const* d_in, const int* in_sizes, int n_in,
                              void* d_out, int out_size, void* d_ws, size_t ws_size,
                              hipStream_t stream) {
  const int*   type_ids  = (const int*)d_in[0];
  const int*   token_ids = (const int*)d_in[1];
  const int*   src       = (const int*)d_in[2];
  const float* lw        = (const float*)d_in[4];
  const float* rw        = (const float*)d_in[5];
  const float* temb      = (const float*)d_in[7];
  const float* kemb      = (const float*)d_in[8];
  const float* Wl        = (const float*)d_in[9];
  const float* Wr        = (const float*)d_in[10];
  const float* Wt        = (const float*)d_in[11];
  const float* bconv     = (const float*)d_in[12];
  const float* Wjm       = (const float*)d_in[13];
  float* out = (float*)d_out;
  char* wsb = (char*)d_ws;

  // workspace layout (regions reused across phases; peak 42 MB)
  float* h     = (float*)(wsb + 0);          // 16.78 MB   (dead after buildU)
  float* WT    = (float*)(wsb + 0);          // 12.5  MB   (overlays h)
  float* feat  = (float*)(wsb + 16777216);   // 16.78 MB   (dead after buildU)
  float* gT    = (float*)(wsb + 16777216);   // 6.55  MB   (overlays feat)
  float* delta = (float*)(wsb + 23330816);   // 6.55  MB
  float* accZ  = (float*)(wsb + 29884416);   // 102 KB
  float* zbuf  = (float*)(wsb + 29986816);   // 102 KB
  float* hl    = (float*)(wsb + 33554432);   // 4.19 MB    (dead after conv)
  float* hr    = (float*)(wsb + 37748736);   // 4.19 MB
  float* l2b   = (float*)(wsb + 33554432);   // 128 KB     (overlays hl)
  int*   sel   = (int*)  (wsb + 33685504);   // 1 KB
  float* U     = (float*)(wsb + 33686528);   // 512 KB
  float* Vsum  = (float*)(wsb + 34210816);   // 512 KB
  float* mw    = (float*)(wsb + 34735104);   // 128 KB
  float* sw    = (float*)(wsb + 34866176);   // 128 KB
  float* SCT   = (float*)(wsb + 34997248);   // 512 KB

  k_embed<<<4096, 256, 0, stream>>>(type_ids, token_ids, temb, kemb, h);

  for (int l = 0; l < NLAY; ++l) {
    k_gather<<<1024, 256, 0, stream>>>(h, src, lw, rw, hl, hr);
    k_conv<<<256, 256, 0, stream>>>(hl, hr, h,
                                    Wl + l * 16384, Wr + l * 16384, Wt + l * 16384,
                                    bconv + l * 128, feat + l * (M_INT * 128));
  }

  k_l2<<<8192, 256, 0, stream>>>(h, feat, l2b);
  k_topk<<<32, 256, 0, stream>>>(l2b, sel);
  k_buildU<<<128, 256, 0, stream>>>(h, feat, sel, U, Vsum);
  k_transW<<<1024, 256, 0, stream>>>(Wjm, WT);   // after buildU: h is dead

  for (int it = 0; it < 3; ++it) {
    k_vtsA<<<256, 1024, 0, stream>>>(U, Vsum, mw, sw);
    k_vtsB<<<256, 1024, 0, stream>>>(U, Vsum, mw, sw, SCT, it == 2 ? 1 : 0);
  }

  for (int it = 0; it < 3; ++it) {
    if (it > 0) k_gamma<<<128, 256, 0, stream>>>(delta, gT);
    hipMemsetAsync(accZ, 0, 32 * 50 * 16 * 4, stream);
    k_zsweep<<<400, 256, 0, stream>>>(WT, SCT, gT, accZ, it == 0 ? 1 : 0);
    k_squash<<<7, 256, 0, stream>>>(accZ, zbuf, out, it == 2 ? 1 : 0);
    if (it < 2) k_dsweep<<<4096, 256, 0, stream>>>(WT, SCT, zbuf, delta, it == 0 ? 1 : 0);
  }
}

// Round 3
// 518.879 us; speedup vs baseline: 1.3259x; 1.0805x over previous
//
#include <hip/hip_runtime.h>

// ---------------------------------------------------------------------------
// TreeCaps forward, MI355X fp32 implementation.
// Fixed forest: per graph of 1024 nodes, node p's children are 4p+1..4p+4;
// nodes 0..255 are internal (updated each layer), 256..1023 are leaves
// (keep embedding h0 through all layers).
// R1: VTS routing kernels widened to 1024-thread blocks.
// R2: k_dsweep restructured to 1 block per node (was 4) -> WT read exactly
//     once (12.5 MB, was ~50 MB of requests / 38.8 MB HBM fetch).
// ---------------------------------------------------------------------------

#define BG      32
#define NPG     1024
#define HH      128
#define NLAY    4
#define INT_PG  256
#define M_INT   8192      // BG*INT_PG
#define NN      32768     // BG*NPG
#define EPG     1023
#define DCC     16
#define NS      50

// ---------------- embedding: h0 = concat(type_emb[t], token_emb[k]) --------
__global__ void k_embed(const int* __restrict__ tids, const int* __restrict__ kids,
                        const float* __restrict__ temb, const float* __restrict__ kemb,
                        float* __restrict__ h) {
  int idx = blockIdx.x * 256 + threadIdx.x;        // NN*32
  int n = idx >> 5, c4 = idx & 31;
  float4 v;
  if (c4 < 16) v = *(const float4*)(temb + tids[n] * 64 + c4 * 4);
  else         v = *(const float4*)(kemb + kids[n] * 64 + (c4 - 16) * 4);
  *(float4*)(h + n * 128 + c4 * 4) = v;
}

// ---------------- per-layer: weighted child sums ---------------------------
__global__ void k_gather(const float* __restrict__ h, const int* __restrict__ src,
                         const float* __restrict__ lw, const float* __restrict__ rw,
                         float* __restrict__ hl, float* __restrict__ hr) {
  int idx = blockIdx.x * 256 + threadIdx.x;        // M_INT*32
  int p = idx >> 5, c4 = idx & 31;
  int g = p >> 8, pl = p & 255;
  float4 al = make_float4(0.f, 0.f, 0.f, 0.f);
  float4 ar = make_float4(0.f, 0.f, 0.f, 0.f);
  for (int j = 0; j < 4; ++j) {
    int cc = 4 * pl + 1 + j;                       // child local id
    if (cc < NPG) {
      int e = g * EPG + cc - 1;
      int child = src[e];                          // global node id
      float lv = lw[e], rv = rw[e];
      float4 hv = *(const float4*)(h + child * 128 + c4 * 4);
      al.x = fmaf(lv, hv.x, al.x); al.y = fmaf(lv, hv.y, al.y);
      al.z = fmaf(lv, hv.z, al.z); al.w = fmaf(lv, hv.w, al.w);
      ar.x = fmaf(rv, hv.x, ar.x); ar.y = fmaf(rv, hv.y, ar.y);
      ar.z = fmaf(rv, hv.z, ar.z); ar.w = fmaf(rv, hv.w, ar.w);
    }
  }
  *(float4*)(hl + p * 128 + c4 * 4) = al;
  *(float4*)(hr + p * 128 + c4 * 4) = ar;
}

// ------------- conv matmul: new_h = relu(hl@Wl + hr@Wr + h@Wt + b) ---------
// [8192 rows, K=384, N=128]; block = 256 thr, 32 rows x 128 cols, 4x4/thread
__global__ __launch_bounds__(256) void k_conv(
    const float* __restrict__ hl, const float* __restrict__ hr,
    float* __restrict__ h,
    const float* __restrict__ Wl, const float* __restrict__ Wr,
    const float* __restrict__ Wt, const float* __restrict__ bias,
    float* __restrict__ feat) {
  __shared__ float Ws[32][128];
  __shared__ float AsT[32][40];   // [k][row], padded
  int tid = threadIdx.x;
  int tx = tid & 31, ty = tid >> 5;
  int rowBase = blockIdx.x * 32;
  int nodeBase = ((rowBase >> 8) << 10) + (rowBase & 255);
  float acc[4][4] = {};
  int sr = tid >> 3, sc4 = (tid & 7) * 4;

  for (int kc = 0; kc < 12; ++kc) {
    int ssel = kc >> 2, kcol = (kc & 3) * 32;
    const float* ap = (ssel == 0) ? (hl + rowBase * 128)
                    : (ssel == 1) ? (hr + rowBase * 128)
                                  : (h + nodeBase * 128);
    const float* wsrc = ((ssel == 0) ? Wl : (ssel == 1) ? Wr : Wt) + kcol * 128;
    float4 av = *(const float4*)(ap + sr * 128 + kcol + sc4);
    float4 wv0, wv1, wv2, wv3;
    {
      int f0 = tid, f1 = tid + 256, f2 = tid + 512, f3 = tid + 768;
      wv0 = *(const float4*)(wsrc + (f0 >> 5) * 128 + (f0 & 31) * 4);
      wv1 = *(const float4*)(wsrc + (f1 >> 5) * 128 + (f1 & 31) * 4);
      wv2 = *(const float4*)(wsrc + (f2 >> 5) * 128 + (f2 & 31) * 4);
      wv3 = *(const float4*)(wsrc + (f3 >> 5) * 128 + (f3 & 31) * 4);
    }
    __syncthreads();
    AsT[sc4 + 0][sr] = av.x; AsT[sc4 + 1][sr] = av.y;
    AsT[sc4 + 2][sr] = av.z; AsT[sc4 + 3][sr] = av.w;
    {
      int f0 = tid, f1 = tid + 256, f2 = tid + 512, f3 = tid + 768;
      *(float4*)&Ws[f0 >> 5][(f0 & 31) * 4] = wv0;
      *(float4*)&Ws[f1 >> 5][(f1 & 31) * 4] = wv1;
      *(float4*)&Ws[f2 >> 5][(f2 & 31) * 4] = wv2;
      *(float4*)&Ws[f3 >> 5][(f3 & 31) * 4] = wv3;
    }
    __syncthreads();
    #pragma unroll
    for (int kk = 0; kk < 32; ++kk) {
      float4 wv = *(float4*)&Ws[kk][tx * 4];
      float4 av2 = *(float4*)&AsT[kk][ty * 4];
      float aa[4] = {av2.x, av2.y, av2.z, av2.w};
      float ww[4] = {wv.x, wv.y, wv.z, wv.w};
      #pragma unroll
      for (int i = 0; i < 4; ++i)
        #pragma unroll
        for (int j = 0; j < 4; ++j)
          acc[i][j] = fmaf(aa[i], ww[j], acc[i][j]);
    }
  }
  float4 bv = *(const float4*)(bias + tx * 4);
  float bb[4] = {bv.x, bv.y, bv.z, bv.w};
  #pragma unroll
  for (int i = 0; i < 4; ++i) {
    int r = ty * 4 + i;
    float4 o = make_float4(fmaxf(acc[i][0] + bb[0], 0.f),
                           fmaxf(acc[i][1] + bb[1], 0.f),
                           fmaxf(acc[i][2] + bb[2], 0.f),
                           fmaxf(acc[i][3] + bb[3], 0.f));
    *(float4*)(feat + (rowBase + r) * 128 + tx * 4) = o;
    *(float4*)(h + (nodeBase + r) * 128 + tx * 4) = o;
  }
}

// ---------------- l2 norms over [H, L] per node ----------------------------
__global__ void k_l2(const float* __restrict__ h, const float* __restrict__ feat,
                     float* __restrict__ l2) {
  int wid = (blockIdx.x * 256 + threadIdx.x) >> 6;   // node id
  int lane = threadIdx.x & 63;
  int g = wid >> 10, local = wid & 1023;
  float s = 0.f;
  if (local >= INT_PG) {                              // leaf: 4*||h0||^2
    const float* p = h + wid * 128;
    float a = p[lane], b = p[lane + 64];
    s = (a * a + b * b) * 4.f;
  } else {
    int row = (g * INT_PG + local) * 128;
    #pragma unroll
    for (int l = 0; l < 4; ++l) {
      const float* p = feat + l * (M_INT * 128) + row;
      float a = p[lane], b = p[lane + 64];
      s += a * a + b * b;
    }
  }
  #pragma unroll
  for (int off = 32; off; off >>= 1) s += __shfl_down(s, off);
  if (lane == 0) l2[wid] = s;
}

// ---------------- top-8 per graph (JAX tie-break: lower index first) -------
__global__ void k_topk(const float* __restrict__ l2, int* __restrict__ sel) {
  __shared__ unsigned long long keys[1024];
  __shared__ unsigned long long red[256];
  int g = blockIdx.x, tid = threadIdx.x;
  for (int i = tid; i < 1024; i += 256) {
    unsigned vb = __float_as_uint(l2[g * 1024 + i]);   // l2 >= 0: uint order ok
    keys[i] = ((unsigned long long)vb << 32) | (unsigned)(~i);
  }
  __syncthreads();
  for (int r = 0; r < 8; ++r) {
    unsigned long long best = 0ULL;
    for (int i = tid; i < 1024; i += 256) {
      unsigned long long k = keys[i];
      best = (k > best) ? k : best;
    }
    red[tid] = best;
    __syncthreads();
    for (int st = 128; st; st >>= 1) {
      if (tid < st) {
        unsigned long long a = red[tid], b = red[tid + st];
        red[tid] = (b > a) ? b : a;
      }
      __syncthreads();
    }
    if (tid == 0) {
      unsigned long long k = red[0];
      int idx = (int)(~(unsigned)(k & 0xffffffffu));
      sel[g * 8 + r] = idx;
      keys[idx] = 0ULL;
    }
    __syncthreads();
  }
}

// ---------------- build U (= initial v_j) [g][1024][4] ---------------------
__global__ void k_buildU(const float* __restrict__ h, const float* __restrict__ feat,
                         const int* __restrict__ sel,
                         float* __restrict__ U, float* __restrict__ Vsum) {
  int idx = blockIdx.x * 256 + threadIdx.x;      // 32768
  int g = idx >> 10, rank = (idx >> 7) & 7, hh = idx & 127;
  int local = sel[g * 8 + rank];
  float4 v;
  if (local >= INT_PG) {
    float x = h[(g * NPG + local) * 128 + hh];
    v = make_float4(x, x, x, x);
  } else {
    int row = (g * INT_PG + local) * 128 + hh;
    v.x = feat[row];
    v.y = feat[M_INT * 128 + row];
    v.z = feat[2 * M_INT * 128 + row];
    v.w = feat[3 * M_INT * 128 + row];
  }
  int o = g * 1024 + rank * 128 + hh;
  ((float4*)U)[o] = v;
  ((float4*)Vsum)[o] = v;
}

// ------------- VTS phase A: per-row softmax stats of alpha = U@Vsum.T ------
// 1024 thr: l = tid&63 -> rows rb+l, rb+64+l; p = tid>>6 -> j in [64p,64p+64)
__global__ __launch_bounds__(1024) void k_vtsA(const float* __restrict__ U,
                                               const float* __restrict__ Vsum,
                                               float* __restrict__ mw, float* __restrict__ sw) {
  __shared__ float4 Vs[1024];     // 16 KB
  __shared__ float2 red[1024];    // 8 KB
  int g = blockIdx.x >> 3, rb = (blockIdx.x & 7) * 128;
  int tid = threadIdx.x, l = tid & 63, p = tid >> 6;
  Vs[tid] = ((const float4*)Vsum)[g * 1024 + tid];
  __syncthreads();
  float4 u0 = ((const float4*)U)[g * 1024 + rb + l];
  float4 u1 = ((const float4*)U)[g * 1024 + rb + 64 + l];
  int j0 = p * 64;
  float m0 = -3.4e38f, m1 = -3.4e38f;
  for (int j = j0; j < j0 + 64; ++j) {
    float4 v = Vs[j];                                  // broadcast across wave
    float a0 = u0.x * v.x + u0.y * v.y + u0.z * v.z + u0.w * v.w;
    float a1 = u1.x * v.x + u1.y * v.y + u1.z * v.z + u1.w * v.w;
    m0 = fmaxf(m0, a0); m1 = fmaxf(m1, a1);
  }
  red[tid] = make_float2(m0, m1);
  __syncthreads();
  #pragma unroll
  for (int st = 512; st >= 64; st >>= 1) {
    if (tid < st) {
      float2 a = red[tid], b = red[tid + st];
      red[tid] = make_float2(fmaxf(a.x, b.x), fmaxf(a.y, b.y));
    }
    __syncthreads();
  }
  float2 mm = red[l];
  __syncthreads();                                     // all reads of red done
  float s0 = 0.f, s1 = 0.f;
  for (int j = j0; j < j0 + 64; ++j) {
    float4 v = Vs[j];
    float a0 = u0.x * v.x + u0.y * v.y + u0.z * v.z + u0.w * v.w;
    float a1 = u1.x * v.x + u1.y * v.y + u1.z * v.z + u1.w * v.w;
    s0 += __expf(a0 - mm.x);
    s1 += __expf(a1 - mm.y);
  }
  red[tid] = make_float2(s0, s1);
  __syncthreads();
  #pragma unroll
  for (int st = 512; st >= 64; st >>= 1) {
    if (tid < st) {
      float2 a = red[tid], b = red[tid + st];
      red[tid] = make_float2(a.x + b.x, a.y + b.y);
    }
    __syncthreads();
  }
  if (tid < 64) {
    float2 ss = red[tid];
    mw[g * 1024 + rb + tid] = mm.x;
    mw[g * 1024 + rb + 64 + tid] = mm.y;
    sw[g * 1024 + rb + tid] = ss.x;
    sw[g * 1024 + rb + 64 + tid] = ss.y;
  }
}

// ------------- VTS phase B: Vnew = beta.T @ U; update Vsum or emit SC ------
// 1024 thr: l = tid&63 -> cols cb+l, cb+64+l; p = tid>>6 -> i in [64p,64p+64)
__global__ __launch_bounds__(1024) void k_vtsB(const float* __restrict__ U,
                                               float* __restrict__ Vsum,
                                               const float* __restrict__ mw,
                                               const float* __restrict__ sw,
                                               float* __restrict__ SCT, int last) {
  __shared__ float4 Us[1024];     // 16 KB
  __shared__ float2 ms[1024];     // 8 KB (m, 1/s)
  __shared__ float4 par[1024];    // 16 KB
  int g = blockIdx.x >> 3, cb = (blockIdx.x & 7) * 128;
  int tid = threadIdx.x, l = tid & 63, p = tid >> 6;
  Us[tid] = ((const float4*)U)[g * 1024 + tid];
  ms[tid] = make_float2(mw[g * 1024 + tid], 1.0f / sw[g * 1024 + tid]);
  __syncthreads();
  float4 v0 = ((const float4*)Vsum)[g * 1024 + cb + l];
  float4 v1 = ((const float4*)Vsum)[g * 1024 + cb + 64 + l];
  float4 acc0 = make_float4(0.f, 0.f, 0.f, 0.f);
  float4 acc1 = make_float4(0.f, 0.f, 0.f, 0.f);
  int i0 = p * 64;
  for (int i = i0; i < i0 + 64; ++i) {
    float4 uu = Us[i];                                 // broadcast across wave
    float2 st = ms[i];
    float a0 = uu.x * v0.x + uu.y * v0.y + uu.z * v0.z + uu.w * v0.w;
    float a1 = uu.x * v1.x + uu.y * v1.y + uu.z * v1.z + uu.w * v1.w;
    float w0 = __expf(a0 - st.x) * st.y;
    float w1 = __expf(a1 - st.x) * st.y;
    acc0.x = fmaf(w0, uu.x, acc0.x); acc0.y = fmaf(w0, uu.y, acc0.y);
    acc0.z = fmaf(w0, uu.z, acc0.z); acc0.w = fmaf(w0, uu.w, acc0.w);
    acc1.x = fmaf(w1, uu.x, acc1.x); acc1.y = fmaf(w1, uu.y, acc1.y);
    acc1.z = fmaf(w1, uu.z, acc1.z); acc1.w = fmaf(w1, uu.w, acc1.w);
  }
  par[tid] = acc0;
  __syncthreads();
  #pragma unroll
  for (int st = 512; st >= 64; st >>= 1) {
    if (tid < st) {
      float4 a = par[tid], b = par[tid + st];
      par[tid] = make_float4(a.x + b.x, a.y + b.y, a.z + b.z, a.w + b.w);
    }
    __syncthreads();
  }
  float4 o0;
  if (tid < 64) o0 = par[tid];
  __syncthreads();
  par[tid] = acc1;
  __syncthreads();
  #pragma unroll
  for (int st = 512; st >= 64; st >>= 1) {
    if (tid < st) {
      float4 a = par[tid], b = par[tid + st];
      par[tid] = make_float4(a.x + b.x, a.y + b.y, a.z + b.z, a.w + b.w);
    }
    __syncthreads();
  }
  if (tid < 64) {
    float4 o1 = par[tid];
    int j0c = cb + tid, j1c = cb + 64 + tid;
    if (last) {
      float sq0 = o0.x * o0.x + o0.y * o0.y + o0.z * o0.z + o0.w * o0.w;
      float f0 = (sq0 / (1.f + sq0)) / (sqrtf(sq0 + 1e-10f) + 1e-8f);
      ((float4*)SCT)[j0c * 32 + g] = make_float4(o0.x * f0, o0.y * f0, o0.z * f0, o0.w * f0);
      float sq1 = o1.x * o1.x + o1.y * o1.y + o1.z * o1.z + o1.w * o1.w;
      float f1 = (sq1 / (1.f + sq1)) / (sqrtf(sq1 + 1e-10f) + 1e-8f);
      ((float4*)SCT)[j1c * 32 + g] = make_float4(o1.x * f1, o1.y * f1, o1.z * f1, o1.w * f1);
    } else {
      float4 w0 = ((const float4*)Vsum)[g * 1024 + j0c];
      float4 w1 = ((const float4*)Vsum)[g * 1024 + j1c];
      ((float4*)Vsum)[g * 1024 + j0c] = make_float4(w0.x + o0.x, w0.y + o0.y,
                                                    w0.z + o0.z, w0.w + o0.w);
      ((float4*)Vsum)[g * 1024 + j1c] = make_float4(w1.x + o1.x, w1.y + o1.y,
                                                    w1.z + o1.z, w1.w + o1.w);
    }
  }
}

// ---------------- Wjm[n][c][s][m] -> W_T[s][n][c][m] -----------------------
__global__ void k_transW(const float* __restrict__ Wjm, float* __restrict__ WT) {
  __shared__ float w[3200];
  int n = blockIdx.x, tid = threadIdx.x;
  for (int i = tid; i < 3200; i += 256) w[i] = Wjm[n * 3200 + i];
  __syncthreads();
  for (int i = tid; i < 3200; i += 256) {
    int s = i >> 6, cm = i & 63, cc = cm >> 2, m = cm & 3;
    WT[(s * 1024 + n) * 64 + cm] = w[(cc * NS + s) * 4 + m];
  }
}

// ---------------- gamma = softmax_s(delta), layouts [s][n][b] --------------
__global__ void k_gamma(const float* __restrict__ delta, float* __restrict__ gT) {
  int idx = blockIdx.x * 256 + threadIdx.x;    // 32768 = (n,b)
  int b = idx & 31, n = idx >> 5;
  const float* dp = delta + n * 32 + b;        // s-stride = 32768 floats
  float m = -3.4e38f;
  for (int s = 0; s < NS; ++s) m = fmaxf(m, dp[s * 32768]);
  float sum = 0.f;
  for (int s = 0; s < NS; ++s) sum += __expf(dp[s * 32768] - m);
  float inv = 1.0f / sum;
  float* gp = gT + n * 32 + b;
  for (int s = 0; s < NS; ++s) gp[s * 32768] = __expf(dp[s * 32768] - m) * inv;
}

// ------------- Z sweep: accZ[b][s][c] += sum_n gamma * v -------------------
__global__ __launch_bounds__(256) void k_zsweep(const float* __restrict__ WT,
                                                const float* __restrict__ SCT,
                                                const float* __restrict__ gT,
                                                float* __restrict__ accZ, int it0) {
  int sb = blockIdx.x >> 3, nb = blockIdx.x & 7;
  int tid = threadIdx.x;
  int b = tid & 31, ch = tid >> 5;             // ch in 0..7: c = ch, ch+8
  int n0 = nb * 128;
  const float4* wt = (const float4*)WT + (sb * 1024 + n0) * 16;
  const float4* sct = (const float4*)SCT + n0 * 32 + b;
  const float* gp = gT + (sb * 1024 + n0) * 32 + b;
  float a0 = 0.f, a1 = 0.f;
  for (int nn = 0; nn < 128; ++nn) {
    float4 w0 = wt[nn * 16 + ch];
    float4 w1 = wt[nn * 16 + ch + 8];
    float4 s4 = sct[nn * 32];
    float gm = it0 ? (1.0f / 50.0f) : gp[nn * 32];
    float t0 = w0.x * s4.x + w0.y * s4.y + w0.z * s4.z + w0.w * s4.w;
    float t1 = w1.x * s4.x + w1.y * s4.y + w1.z * s4.z + w1.w * s4.w;
    a0 = fmaf(gm, t0, a0);
    a1 = fmaf(gm, t1, a1);
  }
  atomicAdd(accZ + (b * NS + sb) * 16 + ch, a0);
  atomicAdd(accZ + (b * NS + sb) * 16 + ch + 8, a1);
}

// ---------------- squash accZ -> z; final: logits --------------------------
__global__ void k_squash(const float* __restrict__ accZ, float* __restrict__ z,
                         float* __restrict__ out, int fin) {
  int idx = blockIdx.x * 256 + threadIdx.x;
  if (idx >= 1600) return;
  const float4* a4 = (const float4*)accZ + idx * 4;
  float4 u0 = a4[0], u1 = a4[1], u2 = a4[2], u3 = a4[3];
  float sq = u0.x * u0.x + u0.y * u0.y + u0.z * u0.z + u0.w * u0.w
           + u1.x * u1.x + u1.y * u1.y + u1.z * u1.z + u1.w * u1.w
           + u2.x * u2.x + u2.y * u2.y + u2.z * u2.z + u2.w * u2.w
           + u3.x * u3.x + u3.y * u3.y + u3.z * u3.z + u3.w * u3.w;
  float f = (sq / (1.f + sq)) / (sqrtf(sq + 1e-10f) + 1e-8f);
  if (fin) {
    float lg = sqrtf(sq * f * f + 1e-10f);
    out[idx] = lg;
    out[idx + 1600] = lg;
  } else {
    float4* z4 = (float4*)z + idx * 4;
    z4[0] = make_float4(u0.x * f, u0.y * f, u0.z * f, u0.w * f);
    z4[1] = make_float4(u1.x * f, u1.y * f, u1.z * f, u1.w * f);
    z4[2] = make_float4(u2.x * f, u2.y * f, u2.z * f, u2.w * f);
    z4[3] = make_float4(u3.x * f, u3.y * f, u3.z * f, u3.w * f);
  }
}

// ------------- D sweep: delta[s][n][b] (+)= sum_c v[b,n,s,c]*z[b,s,c] ------
// R2: one block per node n; WT slice read exactly once grid-wide.
__global__ __launch_bounds__(256) void k_dsweep(const float* __restrict__ WT,
                                                const float* __restrict__ SCT,
                                                const float* __restrict__ z,
                                                float* __restrict__ delta, int first) {
  __shared__ float wl[50 * 64];     // [s][c][m]
  __shared__ float4 scl[32];        // SCT[n][b][:]
  int n = blockIdx.x;
  int tid = threadIdx.x;
  for (int i = tid; i < 3200; i += 256)
    wl[i] = WT[((i >> 6) * 1024 + n) * 64 + (i & 63)];
  if (tid < 32) scl[tid] = ((const float4*)SCT)[n * 32 + tid];
  __syncthreads();
  for (int idx = tid; idx < 1600; idx += 256) {
    int s = idx >> 5, b = idx & 31;              // lanes 0-31: same s (LDS bcast)
    const float4* wp = (const float4*)(wl + s * 64);
    const float4* zp = (const float4*)(z + (b * 50 + s) * 16);
    float4 z0 = zp[0], z1 = zp[1], z2 = zp[2], z3 = zp[3];
    float zs[16] = {z0.x, z0.y, z0.z, z0.w, z1.x, z1.y, z1.z, z1.w,
                    z2.x, z2.y, z2.z, z2.w, z3.x, z3.y, z3.z, z3.w};
    float4 y = make_float4(0.f, 0.f, 0.f, 0.f);
    #pragma unroll
    for (int c = 0; c < 16; ++c) {
      float4 w = wp[c];
      float zc = zs[c];
      y.x = fmaf(zc, w.x, y.x); y.y = fmaf(zc, w.y, y.y);
      y.z = fmaf(zc, w.z, y.z); y.w = fmaf(zc, w.w, y.w);
    }
    float4 sc = scl[b];
    float dd = sc.x * y.x + sc.y * y.y + sc.z * y.z + sc.w * y.w;
    float* dp = delta + (s * 1024 + n) * 32 + b;
    if (first) *dp = dd; else *dp = *dp + dd;
  }
}

// ---------------------------------------------------------------------------
extern "C" void kernel_launch(void* const* d_in, const int* in_sizes, int n_in,
                              void* d_out, int out_size, void* d_ws, size_t ws_size,
                              hipStream_t stream) {
  const int*   type_ids  = (const int*)d_in[0];
  const int*   token_ids = (const int*)d_in[1];
  const int*   src       = (const int*)d_in[2];
  const float* lw        = (const float*)d_in[4];
  const float* rw        = (const float*)d_in[5];
  const float* temb      = (const float*)d_in[7];
  const float* kemb      = (const float*)d_in[8];
  const float* Wl        = (const float*)d_in[9];
  const float* Wr        = (const float*)d_in[10];
  const float* Wt        = (const float*)d_in[11];
  const float* bconv     = (const float*)d_in[12];
  const float* Wjm       = (const float*)d_in[13];
  float* out = (float*)d_out;
  char* wsb = (char*)d_ws;

  // workspace layout (regions reused across phases; peak 42 MB)
  float* h     = (float*)(wsb + 0);          // 16.78 MB   (dead after buildU)
  float* WT    = (float*)(wsb + 0);          // 12.5  MB   (overlays h)
  float* feat  = (float*)(wsb + 16777216);   // 16.78 MB   (dead after buildU)
  float* gT    = (float*)(wsb + 16777216);   // 6.55  MB   (overlays feat)
  float* delta = (float*)(wsb + 23330816);   // 6.55  MB
  float* accZ  = (float*)(wsb + 29884416);   // 102 KB
  float* zbuf  = (float*)(wsb + 29986816);   // 102 KB
  float* hl    = (float*)(wsb + 33554432);   // 4.19 MB    (dead after conv)
  float* hr    = (float*)(wsb + 37748736);   // 4.19 MB
  float* l2b   = (float*)(wsb + 33554432);   // 128 KB     (overlays hl)
  int*   sel   = (int*)  (wsb + 33685504);   // 1 KB
  float* U     = (float*)(wsb + 33686528);   // 512 KB
  float* Vsum  = (float*)(wsb + 34210816);   // 512 KB
  float* mw    = (float*)(wsb + 34735104);   // 128 KB
  float* sw    = (float*)(wsb + 34866176);   // 128 KB
  float* SCT   = (float*)(wsb + 34997248);   // 512 KB

  k_embed<<<4096, 256, 0, stream>>>(type_ids, token_ids, temb, kemb, h);

  for (int l = 0; l < NLAY; ++l) {
    k_gather<<<1024, 256, 0, stream>>>(h, src, lw, rw, hl, hr);
    k_conv<<<256, 256, 0, stream>>>(hl, hr, h,
                                    Wl + l * 16384, Wr + l * 16384, Wt + l * 16384,
                                    bconv + l * 128, feat + l * (M_INT * 128));
  }

  k_l2<<<8192, 256, 0, stream>>>(h, feat, l2b);
  k_topk<<<32, 256, 0, stream>>>(l2b, sel);
  k_buildU<<<128, 256, 0, stream>>>(h, feat, sel, U, Vsum);
  k_transW<<<1024, 256, 0, stream>>>(Wjm, WT);   // after buildU: h is dead

  for (int it = 0; it < 3; ++it) {
    k_vtsA<<<256, 1024, 0, stream>>>(U, Vsum, mw, sw);
    k_vtsB<<<256, 1024, 0, stream>>>(U, Vsum, mw, sw, SCT, it == 2 ? 1 : 0);
  }

  for (int it = 0; it < 3; ++it) {
    if (it > 0) k_gamma<<<128, 256, 0, stream>>>(delta, gT);
    hipMemsetAsync(accZ, 0, 32 * 50 * 16 * 4, stream);
    k_zsweep<<<400, 256, 0, stream>>>(WT, SCT, gT, accZ, it == 0 ? 1 : 0);
    k_squash<<<7, 256, 0, stream>>>(accZ, zbuf, out, it == 2 ? 1 : 0);
    if (it < 2) k_dsweep<<<1024, 256, 0, stream>>>(WT, SCT, zbuf, delta, it == 0 ? 1 : 0);
  }
}